// Round 1
// baseline (1017.995 us; speedup 1.0000x reference)
//
#include <hip/hip_runtime.h>
#include <hip/hip_bf16.h>
#include <cstddef>

#define TOKENS 4096
#define DMODEL 1024
#define DFFN   2048
#define NEXP   8
#define HROWS  (TOKENS + 2 * TOKENS)   // 4096 shared + 8192 expert slots

typedef __attribute__((ext_vector_type(8))) __bf16 bf16x8;
typedef __attribute__((ext_vector_type(4))) float f4_t;

__device__ __forceinline__ unsigned short f2bf(float f) {
  union { float f; unsigned int u; } v; v.f = f;
  unsigned int r = v.u + 0x7FFFu + ((v.u >> 16) & 1u);
  return (unsigned short)(r >> 16);
}

// ---------------- router: 1 wave per token ----------------
__global__ __launch_bounds__(256) void router_kernel(
    const float* __restrict__ x, const float* __restrict__ rw,
    int* __restrict__ topi, float* __restrict__ topw,
    int* __restrict__ c_part, float* __restrict__ p_part) {
  __shared__ float sW[DMODEL * NEXP];
  __shared__ int sc[NEXP];
  __shared__ float sp[NEXP];
  for (int i = threadIdx.x; i < DMODEL * NEXP; i += 256) sW[i] = rw[i];
  if (threadIdx.x < NEXP) { sc[threadIdx.x] = 0; sp[threadIdx.x] = 0.f; }
  __syncthreads();
  int wave = threadIdx.x >> 6, lane = threadIdx.x & 63;
  int t = blockIdx.x * 4 + wave;
  const float* xr = x + (size_t)t * DMODEL;
  float acc[NEXP];
#pragma unroll
  for (int e = 0; e < NEXP; ++e) acc[e] = 0.f;
  for (int i = 0; i < DMODEL / 64; ++i) {
    int d = lane + 64 * i;
    float xv = xr[d];
#pragma unroll
    for (int e = 0; e < NEXP; ++e) acc[e] += xv * sW[d * NEXP + e];
  }
#pragma unroll
  for (int off = 32; off > 0; off >>= 1) {
#pragma unroll
    for (int e = 0; e < NEXP; ++e) acc[e] += __shfl_down(acc[e], off, 64);
  }
  if (lane == 0) {
    float m = acc[0];
#pragma unroll
    for (int e = 1; e < NEXP; ++e) m = fmaxf(m, acc[e]);
    float s = 0.f, p[NEXP];
#pragma unroll
    for (int e = 0; e < NEXP; ++e) { p[e] = expf(acc[e] - m); s += p[e]; }
    float inv = 1.f / s;
    int i1 = 0;
#pragma unroll
    for (int e = 1; e < NEXP; ++e) if (acc[e] > acc[i1]) i1 = e;
    int i2 = (i1 == 0) ? 1 : 0;
#pragma unroll
    for (int e = 0; e < NEXP; ++e) if (e != i1 && acc[e] > acc[i2]) i2 = e;
    float w1 = 1.f / (1.f + expf(acc[i2] - acc[i1]));
    topi[2 * t] = i1; topi[2 * t + 1] = i2;
    topw[2 * t] = w1; topw[2 * t + 1] = 1.f - w1;
    atomicAdd(&sc[i1], 1); atomicAdd(&sc[i2], 1);
#pragma unroll
    for (int e = 0; e < NEXP; ++e) atomicAdd(&sp[e], p[e] * inv);
  }
  __syncthreads();
  if (threadIdx.x < NEXP) {
    c_part[blockIdx.x * NEXP + threadIdx.x] = sc[threadIdx.x];
    p_part[blockIdx.x * NEXP + threadIdx.x] = sp[threadIdx.x];
  }
}

// ---------------- scan: offsets + aux loss ----------------
__global__ void scan_aux_kernel(const int* __restrict__ c_part,
                                const float* __restrict__ p_part,
                                int* __restrict__ counts, int* __restrict__ offsets,
                                float* __restrict__ aux_out) {
  __shared__ int sc[32][NEXP];
  __shared__ float sp[32][NEXP];
  __shared__ int fc[NEXP];
  __shared__ float fp[NEXP];
  int e = threadIdx.x & 7, g = threadIdx.x >> 3;
  int cs = 0; float ps = 0.f;
  for (int b = g; b < TOKENS / 4; b += 32) { cs += c_part[b * NEXP + e]; ps += p_part[b * NEXP + e]; }
  sc[g][e] = cs; sp[g][e] = ps;
  __syncthreads();
  if (threadIdx.x < NEXP) {
    int c = 0; float p = 0.f;
    for (int gg = 0; gg < 32; ++gg) { c += sc[gg][threadIdx.x]; p += sp[gg][threadIdx.x]; }
    fc[threadIdx.x] = c; fp[threadIdx.x] = p;
    counts[threadIdx.x] = c;
  }
  __syncthreads();
  if (threadIdx.x == 0) {
    int off = 0; float aux = 0.f;
    for (int ee = 0; ee < NEXP; ++ee) { offsets[ee] = off; off += fc[ee]; aux += (float)fc[ee] * fp[ee]; }
    aux_out[0] = (float)NEXP * aux / ((float)TOKENS * (float)TOKENS);
  }
}

// ---------------- dispatch: compact per-expert lists ----------------
__global__ void dispatch_kernel(const int* __restrict__ topi, const float* __restrict__ topw,
                                const int* __restrict__ offsets, int* __restrict__ fill,
                                int* __restrict__ token_list, float* __restrict__ weight_list) {
  int t = blockIdx.x * 256 + threadIdx.x;
  if (t >= TOKENS) return;
#pragma unroll
  for (int k = 0; k < 2; ++k) {
    int e = topi[2 * t + k]; float w = topw[2 * t + k];
    int pos = atomicAdd(&fill[e], 1);
    token_list[offsets[e] + pos] = t;
    weight_list[offsets[e] + pos] = w;
  }
}

// ---------------- G1: gate+up GEMM + SwiGLU -> h (bf16) ----------------
#define BK 32
#define LDT 40   // padded LDS row (elements)

__global__ __launch_bounds__(256) void g1_kernel(
    const float* __restrict__ x,
    const float* __restrict__ swg, const float* __restrict__ swu,
    const float* __restrict__ ewg, const float* __restrict__ ewu,
    const int* __restrict__ counts, const int* __restrict__ offsets,
    const int* __restrict__ token_list,
    unsigned short* __restrict__ hbuf) {
  const int NTN = DFFN / 64;  // 32
  int nt_blk = blockIdx.x % NTN;
  int mt = blockIdx.x / NTN;
  int f0 = nt_blk * 64;
  const float *wg, *wu;
  int h_base, tl_base, nvalid;
  bool shared_e;
  if (mt < TOKENS / 64) {
    shared_e = true; wg = swg; wu = swu;
    h_base = mt * 64; tl_base = 0; nvalid = 64;
  } else {
    shared_e = false;
    int em = mt - TOKENS / 64;
    int e = em >> 6, emt = em & 63;
    int cnt = counts[e];
    if (emt * 64 >= cnt) return;
    nvalid = min(64, cnt - emt * 64);
    wg = ewg + (size_t)e * DMODEL * DFFN;
    wu = ewu + (size_t)e * DMODEL * DFFN;
    tl_base = offsets[e] + emt * 64;
    h_base = TOKENS + tl_base;
  }
  __shared__ unsigned short As[64 * LDT];
  __shared__ unsigned short Bg[64 * LDT];
  __shared__ unsigned short Bu[64 * LDT];
  __shared__ int s_tok[64];
  if (threadIdx.x < 64) {
    int tok;
    if (shared_e) tok = h_base + threadIdx.x;
    else tok = (threadIdx.x < nvalid) ? token_list[tl_base + threadIdx.x] : 0;
    s_tok[threadIdx.x] = tok;
  }
  __syncthreads();

  int wv = threadIdx.x >> 6, lane = threadIdx.x & 63;
  int lm = lane & 15, quad = lane >> 4;
  f4_t accg[4], accu[4];
#pragma unroll
  for (int i = 0; i < 4; ++i)
#pragma unroll
    for (int j = 0; j < 4; ++j) { accg[i][j] = 0.f; accu[i][j] = 0.f; }

  int ar = threadIdx.x >> 2;            // 0..63 (A row)
  int ac = (threadIdx.x & 3) * 8;       // 0,8,16,24
  int bk = threadIdx.x >> 3;            // 0..31 (B k)
  int bn = (threadIdx.x & 7) * 8;       // 0..56
  int tokA = s_tok[ar];

  for (int k0 = 0; k0 < DMODEL; k0 += BK) {
    {
      const float* src = x + (size_t)tokA * DMODEL + k0 + ac;
      float4 v0 = *(const float4*)(src);
      float4 v1 = *(const float4*)(src + 4);
      unsigned short* dst = &As[ar * LDT + ac];
      dst[0] = f2bf(v0.x); dst[1] = f2bf(v0.y); dst[2] = f2bf(v0.z); dst[3] = f2bf(v0.w);
      dst[4] = f2bf(v1.x); dst[5] = f2bf(v1.y); dst[6] = f2bf(v1.z); dst[7] = f2bf(v1.w);
    }
    {
      const float* srcg = wg + (size_t)(k0 + bk) * DFFN + f0 + bn;
      const float* srcu = wu + (size_t)(k0 + bk) * DFFN + f0 + bn;
      float4 g0 = *(const float4*)(srcg);
      float4 g1 = *(const float4*)(srcg + 4);
      float4 u0 = *(const float4*)(srcu);
      float4 u1 = *(const float4*)(srcu + 4);
      float gv[8] = {g0.x, g0.y, g0.z, g0.w, g1.x, g1.y, g1.z, g1.w};
      float uv[8] = {u0.x, u0.y, u0.z, u0.w, u1.x, u1.y, u1.z, u1.w};
#pragma unroll
      for (int j = 0; j < 8; ++j) {
        Bg[(bn + j) * LDT + bk] = f2bf(gv[j]);
        Bu[(bn + j) * LDT + bk] = f2bf(uv[j]);
      }
    }
    __syncthreads();
    bf16x8 a = *(const bf16x8*)&As[(wv * 16 + lm) * LDT + quad * 8];
#pragma unroll
    for (int nt = 0; nt < 4; ++nt) {
      bf16x8 bg = *(const bf16x8*)&Bg[(nt * 16 + lm) * LDT + quad * 8];
      bf16x8 bu = *(const bf16x8*)&Bu[(nt * 16 + lm) * LDT + quad * 8];
      accg[nt] = __builtin_amdgcn_mfma_f32_16x16x32_bf16(a, bg, accg[nt], 0, 0, 0);
      accu[nt] = __builtin_amdgcn_mfma_f32_16x16x32_bf16(a, bu, accu[nt], 0, 0, 0);
    }
    __syncthreads();
  }
  int rbase = wv * 16 + quad * 4;
#pragma unroll
  for (int r = 0; r < 4; ++r) {
    int row = rbase + r;
    if (row < nvalid) {
      size_t hoff = (size_t)(h_base + row) * DFFN + f0 + lm;
#pragma unroll
      for (int nt = 0; nt < 4; ++nt) {
        float g = accg[nt][r], u = accu[nt][r];
        float h = g / (1.f + __expf(-g)) * u;
        hbuf[hoff + nt * 16] = f2bf(h);
      }
    }
  }
}

// ---------------- G2: down GEMM + weighted scatter-add ----------------
__global__ __launch_bounds__(256) void g2_kernel(
    const unsigned short* __restrict__ hbuf,
    const float* __restrict__ swd, const float* __restrict__ ewd,
    const int* __restrict__ counts, const int* __restrict__ offsets,
    const int* __restrict__ token_list, const float* __restrict__ weight_list,
    float* __restrict__ out) {
  const int NTN = DMODEL / 64;  // 16
  int nt_blk = blockIdx.x % NTN;
  int mt = blockIdx.x / NTN;
  int d0 = nt_blk * 64;
  const float* wd;
  int h_base, tl_base, nvalid;
  bool shared_e;
  if (mt < TOKENS / 64) {
    shared_e = true; wd = swd;
    h_base = mt * 64; tl_base = 0; nvalid = 64;
  } else {
    shared_e = false;
    int em = mt - TOKENS / 64;
    int e = em >> 6, emt = em & 63;
    int cnt = counts[e];
    if (emt * 64 >= cnt) return;
    nvalid = min(64, cnt - emt * 64);
    wd = ewd + (size_t)e * DFFN * DMODEL;
    tl_base = offsets[e] + emt * 64;
    h_base = TOKENS + tl_base;
  }
  __shared__ unsigned short As[64 * LDT];
  __shared__ unsigned short Bd[64 * LDT];
  __shared__ int s_tok[64];
  __shared__ float s_w[64];
  if (threadIdx.x < 64) {
    if (shared_e) { s_tok[threadIdx.x] = h_base + threadIdx.x; s_w[threadIdx.x] = 1.f; }
    else {
      bool v = threadIdx.x < nvalid;
      s_tok[threadIdx.x] = v ? token_list[tl_base + threadIdx.x] : 0;
      s_w[threadIdx.x] = v ? weight_list[tl_base + threadIdx.x] : 0.f;
    }
  }
  __syncthreads();
  int wv = threadIdx.x >> 6, lane = threadIdx.x & 63;
  int lm = lane & 15, quad = lane >> 4;
  f4_t acc[4];
#pragma unroll
  for (int i = 0; i < 4; ++i)
#pragma unroll
    for (int j = 0; j < 4; ++j) acc[i][j] = 0.f;

  int ar = threadIdx.x >> 2;
  int ac = (threadIdx.x & 3) * 8;
  int arr = min(ar, nvalid - 1);        // clamp: never read past valid compact rows
  int bk = threadIdx.x >> 3;
  int bn = (threadIdx.x & 7) * 8;

  for (int k0 = 0; k0 < DFFN; k0 += BK) {
    {
      const unsigned short* src = hbuf + (size_t)(h_base + arr) * DFFN + k0 + ac;
      *(uint4*)&As[ar * LDT + ac] = *(const uint4*)src;
    }
    {
      const float* srcd = wd + (size_t)(k0 + bk) * DMODEL + d0 + bn;
      float4 d0v = *(const float4*)(srcd);
      float4 d1v = *(const float4*)(srcd + 4);
      float dv[8] = {d0v.x, d0v.y, d0v.z, d0v.w, d1v.x, d1v.y, d1v.z, d1v.w};
#pragma unroll
      for (int j = 0; j < 8; ++j) Bd[(bn + j) * LDT + bk] = f2bf(dv[j]);
    }
    __syncthreads();
    bf16x8 a = *(const bf16x8*)&As[(wv * 16 + lm) * LDT + quad * 8];
#pragma unroll
    for (int nt = 0; nt < 4; ++nt) {
      bf16x8 b = *(const bf16x8*)&Bd[(nt * 16 + lm) * LDT + quad * 8];
      acc[nt] = __builtin_amdgcn_mfma_f32_16x16x32_bf16(a, b, acc[nt], 0, 0, 0);
    }
    __syncthreads();
  }
  int rbase = wv * 16 + quad * 4;
#pragma unroll
  for (int r = 0; r < 4; ++r) {
    int row = rbase + r;
    if (row < nvalid) {
      int t = s_tok[row]; float w = s_w[row];
      float* orow = out + (size_t)t * DMODEL + d0 + lm;
#pragma unroll
      for (int nt = 0; nt < 4; ++nt) atomicAdd(&orow[nt * 16], w * acc[nt][r]);
    }
  }
}

extern "C" void kernel_launch(void* const* d_in, const int* in_sizes, int n_in,
                              void* d_out, int out_size, void* d_ws, size_t ws_size,
                              hipStream_t stream) {
  const float* x   = (const float*)d_in[0];
  const float* swg = (const float*)d_in[1];
  const float* swu = (const float*)d_in[2];
  const float* swd = (const float*)d_in[3];
  const float* ewg = (const float*)d_in[4];
  const float* ewu = (const float*)d_in[5];
  const float* ewd = (const float*)d_in[6];
  const float* rw  = (const float*)d_in[7];
  float* out = (float*)d_out;

  char* ws = (char*)d_ws;
  int*   fill     = (int*)(ws + 0);
  int*   counts   = (int*)(ws + 32);
  int*   offsets  = (int*)(ws + 64);
  int*   topi     = (int*)(ws + 128);
  float* topw     = (float*)(ws + 128 + 32768);
  int*   c_part   = (int*)(ws + 128 + 65536);
  float* p_part   = (float*)(ws + 128 + 98304);
  int*   tok_list = (int*)(ws + 128 + 131072);
  float* w_list   = (float*)(ws + 128 + 163840);
  unsigned short* hbuf = (unsigned short*)(ws + 262144);  // 12288*2048*2 = 50.3 MB

  hipMemsetAsync(d_out, 0, (size_t)out_size * sizeof(float), stream);
  hipMemsetAsync(ws, 0, 32, stream);
  router_kernel<<<TOKENS / 4, 256, 0, stream>>>(x, rw, topi, topw, c_part, p_part);
  scan_aux_kernel<<<1, 256, 0, stream>>>(c_part, p_part, counts, offsets,
                                         out + (size_t)TOKENS * DMODEL);
  dispatch_kernel<<<TOKENS / 256, 256, 0, stream>>>(topi, topw, offsets, fill, tok_list, w_list);
  g1_kernel<<<(DFFN / 64) * (TOKENS / 64 + NEXP * (TOKENS / 64)), 256, 0, stream>>>(
      x, swg, swu, ewg, ewu, counts, offsets, tok_list, hbuf);
  g2_kernel<<<(DMODEL / 64) * (TOKENS / 64 + NEXP * (TOKENS / 64)), 256, 0, stream>>>(
      hbuf, swd, ewd, counts, offsets, tok_list, w_list, out);
}

// Round 2
// 589.754 us; speedup vs baseline: 1.7261x; 1.7261x over previous
//
#include <hip/hip_runtime.h>
#include <hip/hip_bf16.h>
#include <cstddef>
#include <cstdint>

#define TOKENS 4096
#define DMODEL 1024
#define DFFN   2048
#define NEXP   8
#define MAXT_E 72                 // max 128-row expert m-tiles (sum ceil <= 8192/128+8)
#define MT_SH  (TOKENS / 128)     // 32 shared m-tiles
#define MT_ALL (MT_SH + MAXT_E)   // 104

typedef __attribute__((ext_vector_type(8))) __bf16 bf16x8;
typedef __attribute__((ext_vector_type(4))) float f4_t;

__device__ __forceinline__ unsigned short f2bf(float f) {
  union { float f; unsigned int u; } v; v.f = f;
  unsigned int r = v.u + 0x7FFFu + ((v.u >> 16) & 1u);
  return (unsigned short)(r >> 16);
}

__device__ __forceinline__ void glds16(const void* g, void* l) {
  __builtin_amdgcn_global_load_lds((const __attribute__((address_space(1))) void*)g,
                                   (__attribute__((address_space(3))) void*)l, 16, 0, 0);
}

// ---------------- x fp32 -> bf16 ----------------
__global__ __launch_bounds__(256) void convert_x_kernel(const float* __restrict__ x,
                                                        unsigned short* __restrict__ xb) {
  int i = (blockIdx.x * 256 + threadIdx.x) * 8;
  float4 a = *(const float4*)&x[i];
  float4 b = *(const float4*)&x[i + 4];
  union { unsigned short u[8]; uint4 v; } p;
  p.u[0] = f2bf(a.x); p.u[1] = f2bf(a.y); p.u[2] = f2bf(a.z); p.u[3] = f2bf(a.w);
  p.u[4] = f2bf(b.x); p.u[5] = f2bf(b.y); p.u[6] = f2bf(b.z); p.u[7] = f2bf(b.w);
  *(uint4*)&xb[i] = p.v;
}

// ---------------- fp32 [R][C] -> bf16 [C][R] (batched) ----------------
__global__ __launch_bounds__(256) void transpose_kernel(const float* __restrict__ in,
                                                        unsigned short* __restrict__ out,
                                                        int R, int C, size_t bstride) {
  __shared__ unsigned short sT[64][72];   // 72*2=144B row stride (16B multiple)
  const float* src = in + (size_t)blockIdx.z * bstride;
  unsigned short* dst = out + (size_t)blockIdx.z * bstride;
  int c0 = blockIdx.x * 64, r0 = blockIdx.y * 64;
  int tid = threadIdx.x;
#pragma unroll
  for (int it = 0; it < 4; ++it) {
    int r = it * 16 + (tid >> 4);
    int c = (tid & 15) * 4;
    float4 v = *(const float4*)&src[(size_t)(r0 + r) * C + c0 + c];
    sT[c + 0][r] = f2bf(v.x); sT[c + 1][r] = f2bf(v.y);
    sT[c + 2][r] = f2bf(v.z); sT[c + 3][r] = f2bf(v.w);
  }
  __syncthreads();
#pragma unroll
  for (int it = 0; it < 2; ++it) {
    int cc = it * 32 + (tid >> 3);
    int rr = (tid & 7) * 8;
    *(uint4*)&dst[(size_t)(c0 + cc) * R + r0 + rr] = *(const uint4*)&sT[cc][rr];
  }
}

// ---------------- router: 1 wave per token ----------------
__global__ __launch_bounds__(256) void router_kernel(
    const float* __restrict__ x, const float* __restrict__ rw,
    int* __restrict__ topi, float* __restrict__ topw,
    int* __restrict__ c_part, float* __restrict__ p_part) {
  __shared__ float sW[DMODEL * NEXP];
  __shared__ int sc[NEXP];
  __shared__ float sp[NEXP];
  for (int i = threadIdx.x; i < DMODEL * NEXP; i += 256) sW[i] = rw[i];
  if (threadIdx.x < NEXP) { sc[threadIdx.x] = 0; sp[threadIdx.x] = 0.f; }
  __syncthreads();
  int wave = threadIdx.x >> 6, lane = threadIdx.x & 63;
  int t = blockIdx.x * 4 + wave;
  const float* xr = x + (size_t)t * DMODEL;
  float acc[NEXP];
#pragma unroll
  for (int e = 0; e < NEXP; ++e) acc[e] = 0.f;
  for (int i = 0; i < DMODEL / 64; ++i) {
    int d = lane + 64 * i;
    float xv = xr[d];
#pragma unroll
    for (int e = 0; e < NEXP; ++e) acc[e] += xv * sW[d * NEXP + e];
  }
#pragma unroll
  for (int off = 32; off > 0; off >>= 1) {
#pragma unroll
    for (int e = 0; e < NEXP; ++e) acc[e] += __shfl_down(acc[e], off, 64);
  }
  if (lane == 0) {
    float m = acc[0];
#pragma unroll
    for (int e = 1; e < NEXP; ++e) m = fmaxf(m, acc[e]);
    float s = 0.f, p[NEXP];
#pragma unroll
    for (int e = 0; e < NEXP; ++e) { p[e] = expf(acc[e] - m); s += p[e]; }
    float inv = 1.f / s;
    int i1 = 0;
#pragma unroll
    for (int e = 1; e < NEXP; ++e) if (acc[e] > acc[i1]) i1 = e;
    int i2 = (i1 == 0) ? 1 : 0;
#pragma unroll
    for (int e = 0; e < NEXP; ++e) if (e != i1 && acc[e] > acc[i2]) i2 = e;
    float w1 = 1.f / (1.f + expf(acc[i2] - acc[i1]));
    topi[2 * t] = i1; topi[2 * t + 1] = i2;
    topw[2 * t] = w1; topw[2 * t + 1] = 1.f - w1;
    atomicAdd(&sc[i1], 1); atomicAdd(&sc[i2], 1);
#pragma unroll
    for (int e = 0; e < NEXP; ++e) atomicAdd(&sp[e], p[e] * inv);
  }
  __syncthreads();
  if (threadIdx.x < NEXP) {
    c_part[blockIdx.x * NEXP + threadIdx.x] = sc[threadIdx.x];
    p_part[blockIdx.x * NEXP + threadIdx.x] = sp[threadIdx.x];
  }
}

// ---------------- scan: offsets + aux + tile list ----------------
__global__ void scan_aux_kernel(const int* __restrict__ c_part,
                                const float* __restrict__ p_part,
                                int* __restrict__ counts, int* __restrict__ offsets,
                                int* __restrict__ te, int* __restrict__ tb,
                                int* __restrict__ ntl,
                                float* __restrict__ aux_out) {
  __shared__ int sc[32][NEXP];
  __shared__ float sp[32][NEXP];
  __shared__ int fc[NEXP];
  __shared__ float fp[NEXP];
  int e = threadIdx.x & 7, g = threadIdx.x >> 3;
  int cs = 0; float ps = 0.f;
  for (int b = g; b < TOKENS / 4; b += 32) { cs += c_part[b * NEXP + e]; ps += p_part[b * NEXP + e]; }
  sc[g][e] = cs; sp[g][e] = ps;
  __syncthreads();
  if (threadIdx.x < NEXP) {
    int c = 0; float p = 0.f;
    for (int gg = 0; gg < 32; ++gg) { c += sc[gg][threadIdx.x]; p += sp[gg][threadIdx.x]; }
    fc[threadIdx.x] = c; fp[threadIdx.x] = p;
    counts[threadIdx.x] = c;
  }
  __syncthreads();
  if (threadIdx.x == 0) {
    int off = 0; float aux = 0.f; int idx = 0;
    for (int ee = 0; ee < NEXP; ++ee) {
      offsets[ee] = off;
      int nt = (fc[ee] + 127) >> 7;
      for (int t = 0; t < nt; ++t) { te[idx] = ee; tb[idx] = t * 128; ++idx; }
      off += fc[ee];
      aux += (float)fc[ee] * fp[ee];
    }
    ntl[0] = idx;
    aux_out[0] = (float)NEXP * aux / ((float)TOKENS * (float)TOKENS);
  }
}

// ---------------- dispatch: compact per-expert lists ----------------
__global__ void dispatch_kernel(const int* __restrict__ topi, const float* __restrict__ topw,
                                const int* __restrict__ offsets, int* __restrict__ fill,
                                int* __restrict__ token_list, float* __restrict__ weight_list) {
  int t = blockIdx.x * 256 + threadIdx.x;
  if (t >= TOKENS) return;
#pragma unroll
  for (int k = 0; k < 2; ++k) {
    int e = topi[2 * t + k]; float w = topw[2 * t + k];
    int pos = atomicAdd(&fill[e], 1);
    token_list[offsets[e] + pos] = t;
    weight_list[offsets[e] + pos] = w;
  }
}

// ---------------- G1: 128x128x32 MFMA, gate+up fused, SwiGLU -> hbuf bf16 ----------------
__global__ __launch_bounds__(256, 2) void g1_kernel(
    const unsigned short* __restrict__ xb,
    const unsigned short* __restrict__ swgT, const unsigned short* __restrict__ swuT,
    const unsigned short* __restrict__ ewgT, const unsigned short* __restrict__ ewuT,
    const int* __restrict__ counts, const int* __restrict__ offsets,
    const int* __restrict__ te, const int* __restrict__ tb, const int* __restrict__ ntl,
    const int* __restrict__ token_list,
    unsigned short* __restrict__ hbuf) {
  int nt_blk = blockIdx.x & 15;       // 16 n-tiles over DFFN
  int mt = blockIdx.x >> 4;
  int f0 = nt_blk * 128;
  const unsigned short *wgT, *wuT;
  int h_base, tl_base, nvalid;
  bool shared_e;
  if (mt < MT_SH) {
    shared_e = true; wgT = swgT; wuT = swuT;
    h_base = mt * 128; tl_base = 0; nvalid = 128;
  } else {
    int em = mt - MT_SH;
    if (em >= ntl[0]) return;
    int e = te[em], lb = tb[em];
    shared_e = false;
    nvalid = min(128, counts[e] - lb);
    tl_base = offsets[e] + lb;
    h_base = TOKENS + tl_base;
    wgT = ewgT + (size_t)e * (DMODEL * DFFN);
    wuT = ewuT + (size_t)e * (DMODEL * DFFN);
  }
  __shared__ unsigned short sA[128 * 32];
  __shared__ unsigned short sBg[128 * 32];
  __shared__ unsigned short sBu[128 * 32];
  __shared__ int s_tok[128];
  int tid = threadIdx.x;
  if (tid < 128) {
    s_tok[tid] = shared_e ? (h_base + tid) : token_list[tl_base + min(tid, nvalid - 1)];
  }
  __syncthreads();
  int r0 = tid >> 2;              // 0..63
  int ce = (tid & 3) * 8;         // col elems 0,8,16,24
  const unsigned short* pA0 = xb + (size_t)s_tok[r0] * DMODEL + ce;
  const unsigned short* pA1 = xb + (size_t)s_tok[r0 + 64] * DMODEL + ce;
  const unsigned short* pG0 = wgT + (size_t)(f0 + r0) * DMODEL + ce;
  const unsigned short* pG1 = pG0 + (size_t)64 * DMODEL;
  const unsigned short* pU0 = wuT + (size_t)(f0 + r0) * DMODEL + ce;
  const unsigned short* pU1 = pU0 + (size_t)64 * DMODEL;

  int wv = tid >> 6, lane = tid & 63;
  int wm = wv & 1, wn = wv >> 1;
  int lm = lane & 15, quad = lane >> 4;

  f4_t accg[4][4], accu[4][4];
#pragma unroll
  for (int i = 0; i < 4; ++i)
#pragma unroll
    for (int j = 0; j < 4; ++j)
#pragma unroll
      for (int r = 0; r < 4; ++r) { accg[i][j][r] = 0.f; accu[i][j][r] = 0.f; }

  for (int k0 = 0; k0 < DMODEL; k0 += 32) {
    glds16(pA0 + k0, &sA[tid * 8]);
    glds16(pA1 + k0, &sA[2048 + tid * 8]);
    glds16(pG0 + k0, &sBg[tid * 8]);
    glds16(pG1 + k0, &sBg[2048 + tid * 8]);
    glds16(pU0 + k0, &sBu[tid * 8]);
    glds16(pU1 + k0, &sBu[2048 + tid * 8]);
    __syncthreads();
    bf16x8 a[4], bg[4], bu[4];
#pragma unroll
    for (int i = 0; i < 4; ++i) {
      a[i]  = *(const bf16x8*)&sA [(wm * 64 + i * 16 + lm) * 32 + quad * 8];
      bg[i] = *(const bf16x8*)&sBg[(wn * 64 + i * 16 + lm) * 32 + quad * 8];
      bu[i] = *(const bf16x8*)&sBu[(wn * 64 + i * 16 + lm) * 32 + quad * 8];
    }
#pragma unroll
    for (int i = 0; i < 4; ++i)
#pragma unroll
      for (int j = 0; j < 4; ++j) {
        accg[i][j] = __builtin_amdgcn_mfma_f32_16x16x32_bf16(a[i], bg[j], accg[i][j], 0, 0, 0);
        accu[i][j] = __builtin_amdgcn_mfma_f32_16x16x32_bf16(a[i], bu[j], accu[i][j], 0, 0, 0);
      }
    __syncthreads();
  }
#pragma unroll
  for (int i = 0; i < 4; ++i)
#pragma unroll
    for (int r = 0; r < 4; ++r) {
      int row = wm * 64 + i * 16 + quad * 4 + r;
      if (row < nvalid) {
        size_t base = (size_t)(h_base + row) * DFFN + f0 + wn * 64 + lm;
#pragma unroll
        for (int j = 0; j < 4; ++j) {
          float g = accg[i][j][r], u = accu[i][j][r];
          hbuf[base + j * 16] = f2bf(g / (1.f + __expf(-g)) * u);
        }
      }
    }
}

// ---------------- G2: 128x128x32 MFMA down-proj + weighted atomic scatter ----------------
__global__ __launch_bounds__(256, 2) void g2_kernel(
    const unsigned short* __restrict__ hbuf,
    const unsigned short* __restrict__ swdT, const unsigned short* __restrict__ ewdT,
    const int* __restrict__ counts, const int* __restrict__ offsets,
    const int* __restrict__ te, const int* __restrict__ tb, const int* __restrict__ ntl,
    const int* __restrict__ token_list, const float* __restrict__ weight_list,
    float* __restrict__ out) {
  int nt_blk = blockIdx.x & 7;        // 8 n-tiles over DMODEL
  int mt = blockIdx.x >> 3;
  int d0 = nt_blk * 128;
  const unsigned short* wdT;
  int h_base, tl_base, nvalid;
  bool shared_e;
  if (mt < MT_SH) {
    shared_e = true; wdT = swdT;
    h_base = mt * 128; tl_base = 0; nvalid = 128;
  } else {
    int em = mt - MT_SH;
    if (em >= ntl[0]) return;
    int e = te[em], lb = tb[em];
    shared_e = false;
    nvalid = min(128, counts[e] - lb);
    tl_base = offsets[e] + lb;
    h_base = TOKENS + tl_base;
    wdT = ewdT + (size_t)e * (DFFN * DMODEL);
  }
  __shared__ unsigned short sA[128 * 32];
  __shared__ unsigned short sB[128 * 32];
  __shared__ int s_tok[128];
  __shared__ float s_w[128];
  int tid = threadIdx.x;
  if (tid < 128) {
    if (shared_e) { s_tok[tid] = h_base + tid; s_w[tid] = 1.f; }
    else {
      int idx = tl_base + min(tid, nvalid - 1);
      s_tok[tid] = token_list[idx];
      s_w[tid] = weight_list[idx];
    }
  }
  __syncthreads();
  int r0 = tid >> 2;
  int ce = (tid & 3) * 8;
  const unsigned short* pA0 = hbuf + (size_t)(h_base + r0) * DFFN + ce;
  const unsigned short* pA1 = pA0 + (size_t)64 * DFFN;
  const unsigned short* pB0 = wdT + (size_t)(d0 + r0) * DFFN + ce;
  const unsigned short* pB1 = pB0 + (size_t)64 * DFFN;

  int wv = tid >> 6, lane = tid & 63;
  int wm = wv & 1, wn = wv >> 1;
  int lm = lane & 15, quad = lane >> 4;

  f4_t acc[4][4];
#pragma unroll
  for (int i = 0; i < 4; ++i)
#pragma unroll
    for (int j = 0; j < 4; ++j)
#pragma unroll
      for (int r = 0; r < 4; ++r) acc[i][j][r] = 0.f;

  for (int k0 = 0; k0 < DFFN; k0 += 32) {
    glds16(pA0 + k0, &sA[tid * 8]);
    glds16(pA1 + k0, &sA[2048 + tid * 8]);
    glds16(pB0 + k0, &sB[tid * 8]);
    glds16(pB1 + k0, &sB[2048 + tid * 8]);
    __syncthreads();
    bf16x8 a[4], b[4];
#pragma unroll
    for (int i = 0; i < 4; ++i) {
      a[i] = *(const bf16x8*)&sA[(wm * 64 + i * 16 + lm) * 32 + quad * 8];
      b[i] = *(const bf16x8*)&sB[(wn * 64 + i * 16 + lm) * 32 + quad * 8];
    }
#pragma unroll
    for (int i = 0; i < 4; ++i)
#pragma unroll
      for (int j = 0; j < 4; ++j)
        acc[i][j] = __builtin_amdgcn_mfma_f32_16x16x32_bf16(a[i], b[j], acc[i][j], 0, 0, 0);
    __syncthreads();
  }
#pragma unroll
  for (int i = 0; i < 4; ++i)
#pragma unroll
    for (int r = 0; r < 4; ++r) {
      int row = wm * 64 + i * 16 + quad * 4 + r;
      if (row < nvalid) {
        int t = s_tok[row]; float w = s_w[row];
        float* orow = out + (size_t)t * DMODEL + d0 + wn * 64 + lm;
#pragma unroll
        for (int j = 0; j < 4; ++j) atomicAdd(&orow[j * 16], w * acc[i][j][r]);
      }
    }
}

extern "C" void kernel_launch(void* const* d_in, const int* in_sizes, int n_in,
                              void* d_out, int out_size, void* d_ws, size_t ws_size,
                              hipStream_t stream) {
  const float* x   = (const float*)d_in[0];
  const float* swg = (const float*)d_in[1];
  const float* swu = (const float*)d_in[2];
  const float* swd = (const float*)d_in[3];
  const float* ewg = (const float*)d_in[4];
  const float* ewu = (const float*)d_in[5];
  const float* ewd = (const float*)d_in[6];
  const float* rw  = (const float*)d_in[7];
  float* out = (float*)d_out;

  char* ws = (char*)d_ws;
  const size_t MB = 1048576;
  int*   fill     = (int*)(ws + 0);          // 32 B
  int*   counts   = (int*)(ws + 64);
  int*   offsets  = (int*)(ws + 128);
  int*   ntl      = (int*)(ws + 192);
  int*   te       = (int*)(ws + 256);        // 72 ints
  int*   tb       = (int*)(ws + 1024);       // 72 ints
  int*   topi     = (int*)(ws + 65536);      // 32 KB
  float* topw     = (float*)(ws + 98304);
  int*   c_part   = (int*)(ws + 131072);     // 32 KB
  float* p_part   = (float*)(ws + 163840);
  int*   tok_list = (int*)(ws + 196608);
  float* w_list   = (float*)(ws + 229376);
  unsigned short* xb   = (unsigned short*)(ws + 262144);     // 8 MB
  unsigned short* swgT = (unsigned short*)(ws + 16 * MB);    // 4 MB each
  unsigned short* swuT = (unsigned short*)(ws + 20 * MB);
  unsigned short* swdT = (unsigned short*)(ws + 24 * MB);
  unsigned short* ewgT = (unsigned short*)(ws + 28 * MB);    // 32 MB each
  unsigned short* ewuT = (unsigned short*)(ws + 60 * MB);
  unsigned short* ewdT = (unsigned short*)(ws + 92 * MB);
  unsigned short* hbuf = (unsigned short*)(ws + 124 * MB);   // (12288+128)*2048*2 = 48.5 MB

  hipMemsetAsync(d_out, 0, (size_t)out_size * sizeof(float), stream);
  hipMemsetAsync(ws, 0, 32, stream);

  convert_x_kernel<<<TOKENS * DMODEL / (256 * 8), 256, 0, stream>>>(x, xb);
  transpose_kernel<<<dim3(32, 16, 1), 256, 0, stream>>>(swg, swgT, 1024, 2048, 0);
  transpose_kernel<<<dim3(32, 16, 1), 256, 0, stream>>>(swu, swuT, 1024, 2048, 0);
  transpose_kernel<<<dim3(16, 32, 1), 256, 0, stream>>>(swd, swdT, 2048, 1024, 0);
  transpose_kernel<<<dim3(32, 16, 8), 256, 0, stream>>>(ewg, ewgT, 1024, 2048, (size_t)DMODEL * DFFN);
  transpose_kernel<<<dim3(32, 16, 8), 256, 0, stream>>>(ewu, ewuT, 1024, 2048, (size_t)DMODEL * DFFN);
  transpose_kernel<<<dim3(16, 32, 8), 256, 0, stream>>>(ewd, ewdT, 2048, 1024, (size_t)DFFN * DMODEL);

  router_kernel<<<TOKENS / 4, 256, 0, stream>>>(x, rw, topi, topw, c_part, p_part);
  scan_aux_kernel<<<1, 256, 0, stream>>>(c_part, p_part, counts, offsets, te, tb, ntl,
                                         out + (size_t)TOKENS * DMODEL);
  dispatch_kernel<<<TOKENS / 256, 256, 0, stream>>>(topi, topw, offsets, fill, tok_list, w_list);

  g1_kernel<<<MT_ALL * 16, 256, 0, stream>>>(xb, swgT, swuT, ewgT, ewuT,
                                             counts, offsets, te, tb, ntl, tok_list, hbuf);
  g2_kernel<<<MT_ALL * 8, 256, 0, stream>>>(hbuf, swdT, ewdT,
                                            counts, offsets, te, tb, ntl, tok_list, w_list, out);
}

// Round 3
// 586.327 us; speedup vs baseline: 1.7362x; 1.0058x over previous
//
#include <hip/hip_runtime.h>
#include <hip/hip_bf16.h>
#include <cstddef>
#include <cstdint>

#define TOKENS 4096
#define DMODEL 1024
#define DFFN   2048
#define NEXP   8
#define MAXT_E 72                 // max 128-row expert m-tiles
#define MT_SH  (TOKENS / 128)     // 32 shared m-tiles
#define MT_ALL (MT_SH + MAXT_E)   // 104

typedef __attribute__((ext_vector_type(8))) __bf16 bf16x8;
typedef __attribute__((ext_vector_type(4))) float f4_t;
typedef __attribute__((ext_vector_type(4))) unsigned short us4;

__device__ __forceinline__ unsigned short f2bf(float f) {
  union { float f; unsigned int u; } v; v.f = f;
  unsigned int r = v.u + 0x7FFFu + ((v.u >> 16) & 1u);
  return (unsigned short)(r >> 16);
}

__device__ __forceinline__ void glds16(const void* g, void* l) {
  __builtin_amdgcn_global_load_lds((const __attribute__((address_space(1))) void*)g,
                                   (__attribute__((address_space(3))) void*)l, 16, 0, 0);
}

// ---------------- fused pre-pass: x fp32->bf16 copy + 6 weight transposes ----------------
// block ranges (256 threads each):
//   [0, 2048)                : convert x (2048 blocks * 2048 elems)
//   then 64x64 transpose tiles: swg 512, swu 512, swd 512, ewg 4096, ewu 4096, ewd 4096
#define CONV_BLKS 2048
__global__ __launch_bounds__(256) void prepass_kernel(
    const float* __restrict__ x, unsigned short* __restrict__ xb,
    const float* __restrict__ swg, unsigned short* __restrict__ swgT,
    const float* __restrict__ swu, unsigned short* __restrict__ swuT,
    const float* __restrict__ swd, unsigned short* __restrict__ swdT,
    const float* __restrict__ ewg, unsigned short* __restrict__ ewgT,
    const float* __restrict__ ewu, unsigned short* __restrict__ ewuT,
    const float* __restrict__ ewd, unsigned short* __restrict__ ewdT) {
  __shared__ float sF[64][65];
  int b = blockIdx.x, tid = threadIdx.x;
  if (b < CONV_BLKS) {
    int i = b * 2048 + tid * 8;
    float4 a = *(const float4*)&x[i];
    float4 c = *(const float4*)&x[i + 4];
    union { unsigned short u[8]; uint4 v; } p;
    p.u[0] = f2bf(a.x); p.u[1] = f2bf(a.y); p.u[2] = f2bf(a.z); p.u[3] = f2bf(a.w);
    p.u[4] = f2bf(c.x); p.u[5] = f2bf(c.y); p.u[6] = f2bf(c.z); p.u[7] = f2bf(c.w);
    *(uint4*)&xb[i] = p.v;
    return;
  }
  b -= CONV_BLKS;
  const float* src; unsigned short* dst; int R, C;
  if (b < 512)       { src = swg; dst = swgT; R = 1024; C = 2048; }
  else if (b < 1024) { b -= 512;  src = swu; dst = swuT; R = 1024; C = 2048; }
  else if (b < 1536) { b -= 1024; src = swd; dst = swdT; R = 2048; C = 1024; }
  else if (b < 5632) { b -= 1536; int e = b >> 9; b &= 511;
                       src = ewg + (size_t)e * (DMODEL * DFFN); dst = ewgT + (size_t)e * (DMODEL * DFFN);
                       R = 1024; C = 2048; }
  else if (b < 9728) { b -= 5632; int e = b >> 9; b &= 511;
                       src = ewu + (size_t)e * (DMODEL * DFFN); dst = ewuT + (size_t)e * (DMODEL * DFFN);
                       R = 1024; C = 2048; }
  else               { b -= 9728; int e = b >> 9; b &= 511;
                       src = ewd + (size_t)e * (DFFN * DMODEL); dst = ewdT + (size_t)e * (DFFN * DMODEL);
                       R = 2048; C = 1024; }
  int log_tc = (C == 2048) ? 5 : 4;
  int tr = b >> log_tc, tc = b & ((1 << log_tc) - 1);
  int r0 = tr * 64, c0 = tc * 64;
  // load 64x64 fp32 tile into LDS [r][c], stride 65 (~2-way conflicts = free)
#pragma unroll
  for (int it = 0; it < 4; ++it) {
    int r = it * 16 + (tid >> 4);
    int c = (tid & 15) * 4;
    float4 v = *(const float4*)&src[(size_t)(r0 + r) * C + c0 + c];
    sF[r][c + 0] = v.x; sF[r][c + 1] = v.y; sF[r][c + 2] = v.z; sF[r][c + 3] = v.w;
  }
  __syncthreads();
  // write transposed bf16: thread -> out row (c0+cc), 16 contiguous r
  int cc = tid >> 2, rr = (tid & 3) * 16;
  union { unsigned short u[8]; uint4 v; } p0, p1;
#pragma unroll
  for (int i = 0; i < 8; ++i) p0.u[i] = f2bf(sF[rr + i][cc]);
#pragma unroll
  for (int i = 0; i < 8; ++i) p1.u[i] = f2bf(sF[rr + 8 + i][cc]);
  unsigned short* drow = dst + (size_t)(c0 + cc) * R + r0 + rr;
  *(uint4*)drow = p0.v;
  *(uint4*)(drow + 8) = p1.v;
}

// ---------------- router: 1 wave per token ----------------
__global__ __launch_bounds__(256) void router_kernel(
    const float* __restrict__ x, const float* __restrict__ rw,
    int* __restrict__ topi, float* __restrict__ topw,
    int* __restrict__ c_part, float* __restrict__ p_part) {
  __shared__ float sW[DMODEL * NEXP];
  __shared__ int sc[NEXP];
  __shared__ float sp[NEXP];
  for (int i = threadIdx.x; i < DMODEL * NEXP; i += 256) sW[i] = rw[i];
  if (threadIdx.x < NEXP) { sc[threadIdx.x] = 0; sp[threadIdx.x] = 0.f; }
  __syncthreads();
  int wave = threadIdx.x >> 6, lane = threadIdx.x & 63;
  int t = blockIdx.x * 4 + wave;
  const float* xr = x + (size_t)t * DMODEL;
  float acc[NEXP];
#pragma unroll
  for (int e = 0; e < NEXP; ++e) acc[e] = 0.f;
  for (int i = 0; i < DMODEL / 64; ++i) {
    int d = lane + 64 * i;
    float xv = xr[d];
#pragma unroll
    for (int e = 0; e < NEXP; ++e) acc[e] += xv * sW[d * NEXP + e];
  }
#pragma unroll
  for (int off = 32; off > 0; off >>= 1) {
#pragma unroll
    for (int e = 0; e < NEXP; ++e) acc[e] += __shfl_down(acc[e], off, 64);
  }
  if (lane == 0) {
    float m = acc[0];
#pragma unroll
    for (int e = 1; e < NEXP; ++e) m = fmaxf(m, acc[e]);
    float s = 0.f, p[NEXP];
#pragma unroll
    for (int e = 0; e < NEXP; ++e) { p[e] = expf(acc[e] - m); s += p[e]; }
    float inv = 1.f / s;
    int i1 = 0;
#pragma unroll
    for (int e = 1; e < NEXP; ++e) if (acc[e] > acc[i1]) i1 = e;
    int i2 = (i1 == 0) ? 1 : 0;
#pragma unroll
    for (int e = 0; e < NEXP; ++e) if (e != i1 && acc[e] > acc[i2]) i2 = e;
    float w1 = 1.f / (1.f + expf(acc[i2] - acc[i1]));
    topi[2 * t] = i1; topi[2 * t + 1] = i2;
    topw[2 * t] = w1; topw[2 * t + 1] = 1.f - w1;
    atomicAdd(&sc[i1], 1); atomicAdd(&sc[i2], 1);
#pragma unroll
    for (int e = 0; e < NEXP; ++e) atomicAdd(&sp[e], p[e] * inv);
  }
  __syncthreads();
  if (threadIdx.x < NEXP) {
    c_part[blockIdx.x * NEXP + threadIdx.x] = sc[threadIdx.x];
    p_part[blockIdx.x * NEXP + threadIdx.x] = sp[threadIdx.x];
  }
}

// ---------------- scan: offsets + aux + tile list ----------------
__global__ void scan_aux_kernel(const int* __restrict__ c_part,
                                const float* __restrict__ p_part,
                                int* __restrict__ counts, int* __restrict__ offsets,
                                int* __restrict__ te, int* __restrict__ tb,
                                int* __restrict__ ntl,
                                float* __restrict__ aux_out) {
  __shared__ int sc[32][NEXP];
  __shared__ float sp[32][NEXP];
  __shared__ int fc[NEXP];
  __shared__ float fp[NEXP];
  int e = threadIdx.x & 7, g = threadIdx.x >> 3;
  int cs = 0; float ps = 0.f;
  for (int b = g; b < TOKENS / 4; b += 32) { cs += c_part[b * NEXP + e]; ps += p_part[b * NEXP + e]; }
  sc[g][e] = cs; sp[g][e] = ps;
  __syncthreads();
  if (threadIdx.x < NEXP) {
    int c = 0; float p = 0.f;
    for (int gg = 0; gg < 32; ++gg) { c += sc[gg][threadIdx.x]; p += sp[gg][threadIdx.x]; }
    fc[threadIdx.x] = c; fp[threadIdx.x] = p;
    counts[threadIdx.x] = c;
  }
  __syncthreads();
  if (threadIdx.x == 0) {
    int off = 0; float aux = 0.f; int idx = 0;
    for (int ee = 0; ee < NEXP; ++ee) {
      offsets[ee] = off;
      int nt = (fc[ee] + 127) >> 7;
      for (int t = 0; t < nt; ++t) { te[idx] = ee; tb[idx] = t * 128; ++idx; }
      off += fc[ee];
      aux += (float)fc[ee] * fp[ee];
    }
    ntl[0] = idx;
    aux_out[0] = (float)NEXP * aux / ((float)TOKENS * (float)TOKENS);
  }
}

// ---------------- dispatch: compact per-expert lists ----------------
__global__ void dispatch_kernel(const int* __restrict__ topi, const float* __restrict__ topw,
                                const int* __restrict__ offsets, int* __restrict__ fill,
                                int* __restrict__ token_list, float* __restrict__ weight_list) {
  int t = blockIdx.x * 256 + threadIdx.x;
  if (t >= TOKENS) return;
#pragma unroll
  for (int k = 0; k < 2; ++k) {
    int e = topi[2 * t + k]; float w = topw[2 * t + k];
    int pos = atomicAdd(&fill[e], 1);
    token_list[offsets[e] + pos] = t;
    weight_list[offsets[e] + pos] = w;
  }
}

// ---------------- G1: swapped (A = W^T rows=ffn, B = x cols=tokens), 512 thr ----------------
__global__ __launch_bounds__(512, 4) void g1_kernel(
    const unsigned short* __restrict__ xb,
    const unsigned short* __restrict__ swgT, const unsigned short* __restrict__ swuT,
    const unsigned short* __restrict__ ewgT, const unsigned short* __restrict__ ewuT,
    const int* __restrict__ counts, const int* __restrict__ offsets,
    const int* __restrict__ te, const int* __restrict__ tb, const int* __restrict__ ntl,
    const int* __restrict__ token_list,
    unsigned short* __restrict__ hbuf) {
  int ff_blk = blockIdx.x & 15;       // 16 ffn-tiles over DFFN (M dim)
  int mt = blockIdx.x >> 4;           // token tile (N dim)
  int f0 = ff_blk * 128;
  const unsigned short *wgT, *wuT;
  int h_base, tl_base, nvalid;
  bool shared_e;
  if (mt < MT_SH) {
    shared_e = true; wgT = swgT; wuT = swuT;
    h_base = mt * 128; tl_base = 0; nvalid = 128;
  } else {
    int em = mt - MT_SH;
    if (em >= ntl[0]) return;
    int e = te[em], lb = tb[em];
    shared_e = false;
    nvalid = min(128, counts[e] - lb);
    tl_base = offsets[e] + lb;
    h_base = TOKENS + tl_base;
    wgT = ewgT + (size_t)e * (DMODEL * DFFN);
    wuT = ewuT + (size_t)e * (DMODEL * DFFN);
  }
  __shared__ unsigned short sAg[128 * 32];   // gate weights [ffn][k]
  __shared__ unsigned short sAu[128 * 32];   // up weights   [ffn][k]
  __shared__ unsigned short sB[128 * 32];    // x            [token][k]
  __shared__ int s_tok[128];
  int tid = threadIdx.x;
  if (tid < 128) {
    s_tok[tid] = shared_e ? (h_base + tid) : token_list[tl_base + min(tid, nvalid - 1)];
  }
  __syncthreads();
  int row = tid >> 2;             // 0..127
  int ce = (tid & 3) * 8;
  const unsigned short* pG = wgT + (size_t)(f0 + row) * DMODEL + ce;
  const unsigned short* pU = wuT + (size_t)(f0 + row) * DMODEL + ce;
  const unsigned short* pB = xb + (size_t)s_tok[row] * DMODEL + ce;

  int wv = tid >> 6, lane = tid & 63;
  int wm = wv & 1, wn = wv >> 1;  // wm: ffn half (64), wn: token quarter (32)
  int lm = lane & 15, quad = lane >> 4;

  f4_t accg[4][2], accu[4][2];
#pragma unroll
  for (int i = 0; i < 4; ++i)
#pragma unroll
    for (int j = 0; j < 2; ++j)
#pragma unroll
      for (int r = 0; r < 4; ++r) { accg[i][j][r] = 0.f; accu[i][j][r] = 0.f; }

  for (int k0 = 0; k0 < DMODEL; k0 += 32) {
    glds16(pG + k0, &sAg[tid * 8]);
    glds16(pU + k0, &sAu[tid * 8]);
    glds16(pB + k0, &sB[tid * 8]);
    __syncthreads();
    bf16x8 b0 = *(const bf16x8*)&sB[(wn * 32 + lm) * 32 + quad * 8];
    bf16x8 b1 = *(const bf16x8*)&sB[(wn * 32 + 16 + lm) * 32 + quad * 8];
#pragma unroll
    for (int i = 0; i < 4; ++i) {
      bf16x8 ag = *(const bf16x8*)&sAg[(wm * 64 + i * 16 + lm) * 32 + quad * 8];
      bf16x8 au = *(const bf16x8*)&sAu[(wm * 64 + i * 16 + lm) * 32 + quad * 8];
      accg[i][0] = __builtin_amdgcn_mfma_f32_16x16x32_bf16(ag, b0, accg[i][0], 0, 0, 0);
      accg[i][1] = __builtin_amdgcn_mfma_f32_16x16x32_bf16(ag, b1, accg[i][1], 0, 0, 0);
      accu[i][0] = __builtin_amdgcn_mfma_f32_16x16x32_bf16(au, b0, accu[i][0], 0, 0, 0);
      accu[i][1] = __builtin_amdgcn_mfma_f32_16x16x32_bf16(au, b1, accu[i][1], 0, 0, 0);
    }
    __syncthreads();
  }
  // C/D: col(token) = lane&15, row(ffn) = quad*4 + r  -> pack 4 ffn-contiguous bf16
#pragma unroll
  for (int j = 0; j < 2; ++j) {
    int tok = wn * 32 + j * 16 + lm;
    if (tok < nvalid) {
      unsigned short* hrow = hbuf + (size_t)(h_base + tok) * DFFN + f0 + wm * 64 + quad * 4;
#pragma unroll
      for (int i = 0; i < 4; ++i) {
        us4 h4;
#pragma unroll
        for (int r = 0; r < 4; ++r) {
          float g = accg[i][j][r], u = accu[i][j][r];
          h4[r] = f2bf(g / (1.f + __expf(-g)) * u);
        }
        *(us4*)(hrow + i * 16) = h4;
      }
    }
  }
}

// ---------------- G2: down-proj (A = h tokens, B = wdT), 512 thr, atomic scatter ----------------
__global__ __launch_bounds__(512, 4) void g2_kernel(
    const unsigned short* __restrict__ hbuf,
    const unsigned short* __restrict__ swdT, const unsigned short* __restrict__ ewdT,
    const int* __restrict__ counts, const int* __restrict__ offsets,
    const int* __restrict__ te, const int* __restrict__ tb, const int* __restrict__ ntl,
    const int* __restrict__ token_list, const float* __restrict__ weight_list,
    float* __restrict__ out) {
  int nt_blk = blockIdx.x & 7;        // 8 n-tiles over DMODEL
  int mt = blockIdx.x >> 3;
  int d0 = nt_blk * 128;
  const unsigned short* wdT;
  int h_base, tl_base, nvalid;
  bool shared_e;
  if (mt < MT_SH) {
    shared_e = true; wdT = swdT;
    h_base = mt * 128; tl_base = 0; nvalid = 128;
  } else {
    int em = mt - MT_SH;
    if (em >= ntl[0]) return;
    int e = te[em], lb = tb[em];
    shared_e = false;
    nvalid = min(128, counts[e] - lb);
    tl_base = offsets[e] + lb;
    h_base = TOKENS + tl_base;
    wdT = ewdT + (size_t)e * (DFFN * DMODEL);
  }
  __shared__ unsigned short sA[128 * 32];
  __shared__ unsigned short sB[128 * 32];
  __shared__ int s_tok[128];
  __shared__ float s_w[128];
  int tid = threadIdx.x;
  if (tid < 128) {
    if (shared_e) { s_tok[tid] = h_base + tid; s_w[tid] = 1.f; }
    else {
      int idx = tl_base + min(tid, nvalid - 1);
      s_tok[tid] = token_list[idx];
      s_w[tid] = weight_list[idx];
    }
  }
  __syncthreads();
  int row = tid >> 2;
  int ce = (tid & 3) * 8;
  const unsigned short* pA = hbuf + (size_t)(h_base + row) * DFFN + ce;
  const unsigned short* pB = wdT + (size_t)(d0 + row) * DFFN + ce;

  int wv = tid >> 6, lane = tid & 63;
  int wm = wv & 1, wn = wv >> 1;
  int lm = lane & 15, quad = lane >> 4;

  f4_t acc[4][2];
#pragma unroll
  for (int i = 0; i < 4; ++i)
#pragma unroll
    for (int j = 0; j < 2; ++j)
#pragma unroll
      for (int r = 0; r < 4; ++r) acc[i][j][r] = 0.f;

  for (int k0 = 0; k0 < DFFN; k0 += 32) {
    glds16(pA + k0, &sA[tid * 8]);
    glds16(pB + k0, &sB[tid * 8]);
    __syncthreads();
    bf16x8 b0 = *(const bf16x8*)&sB[(wn * 32 + lm) * 32 + quad * 8];
    bf16x8 b1 = *(const bf16x8*)&sB[(wn * 32 + 16 + lm) * 32 + quad * 8];
#pragma unroll
    for (int i = 0; i < 4; ++i) {
      bf16x8 a = *(const bf16x8*)&sA[(wm * 64 + i * 16 + lm) * 32 + quad * 8];
      acc[i][0] = __builtin_amdgcn_mfma_f32_16x16x32_bf16(a, b0, acc[i][0], 0, 0, 0);
      acc[i][1] = __builtin_amdgcn_mfma_f32_16x16x32_bf16(a, b1, acc[i][1], 0, 0, 0);
    }
    __syncthreads();
  }
  // C/D: col(dmodel) = lane&15, row(token) = quad*4 + r
#pragma unroll
  for (int i = 0; i < 4; ++i)
#pragma unroll
    for (int r = 0; r < 4; ++r) {
      int rw = wm * 64 + i * 16 + quad * 4 + r;
      if (rw < nvalid) {
        int t = s_tok[rw]; float w = s_w[rw];
        float* orow = out + (size_t)t * DMODEL + d0 + wn * 32 + lm;
        atomicAdd(&orow[0], w * acc[i][0][r]);
        atomicAdd(&orow[16], w * acc[i][1][r]);
      }
    }
}

extern "C" void kernel_launch(void* const* d_in, const int* in_sizes, int n_in,
                              void* d_out, int out_size, void* d_ws, size_t ws_size,
                              hipStream_t stream) {
  const float* x   = (const float*)d_in[0];
  const float* swg = (const float*)d_in[1];
  const float* swu = (const float*)d_in[2];
  const float* swd = (const float*)d_in[3];
  const float* ewg = (const float*)d_in[4];
  const float* ewu = (const float*)d_in[5];
  const float* ewd = (const float*)d_in[6];
  const float* rw  = (const float*)d_in[7];
  float* out = (float*)d_out;

  char* ws = (char*)d_ws;
  const size_t MB = 1048576;
  int*   fill     = (int*)(ws + 0);          // 32 B
  int*   counts   = (int*)(ws + 64);
  int*   offsets  = (int*)(ws + 128);
  int*   ntl      = (int*)(ws + 192);
  int*   te       = (int*)(ws + 256);
  int*   tb       = (int*)(ws + 1024);
  int*   topi     = (int*)(ws + 65536);
  float* topw     = (float*)(ws + 98304);
  int*   c_part   = (int*)(ws + 131072);
  float* p_part   = (float*)(ws + 163840);
  int*   tok_list = (int*)(ws + 196608);
  float* w_list   = (float*)(ws + 229376);
  unsigned short* xb   = (unsigned short*)(ws + 262144);     // 8 MB
  unsigned short* swgT = (unsigned short*)(ws + 16 * MB);
  unsigned short* swuT = (unsigned short*)(ws + 20 * MB);
  unsigned short* swdT = (unsigned short*)(ws + 24 * MB);
  unsigned short* ewgT = (unsigned short*)(ws + 28 * MB);
  unsigned short* ewuT = (unsigned short*)(ws + 60 * MB);
  unsigned short* ewdT = (unsigned short*)(ws + 92 * MB);
  unsigned short* hbuf = (unsigned short*)(ws + 124 * MB);

  hipMemsetAsync(d_out, 0, (size_t)out_size * sizeof(float), stream);
  hipMemsetAsync(ws, 0, 32, stream);

  prepass_kernel<<<CONV_BLKS + 13824, 256, 0, stream>>>(
      x, xb, swg, swgT, swu, swuT, swd, swdT, ewg, ewgT, ewu, ewuT, ewd, ewdT);
  router_kernel<<<TOKENS / 4, 256, 0, stream>>>(x, rw, topi, topw, c_part, p_part);
  scan_aux_kernel<<<1, 256, 0, stream>>>(c_part, p_part, counts, offsets, te, tb, ntl,
                                         out + (size_t)TOKENS * DMODEL);
  dispatch_kernel<<<TOKENS / 256, 256, 0, stream>>>(topi, topw, offsets, fill, tok_list, w_list);

  g1_kernel<<<MT_ALL * 16, 512, 0, stream>>>(xb, swgT, swuT, ewgT, ewuT,
                                             counts, offsets, te, tb, ntl, tok_list, hbuf);
  g2_kernel<<<MT_ALL * 8, 512, 0, stream>>>(hbuf, swdT, ewdT,
                                            counts, offsets, te, tb, ntl, tok_list, w_list, out);
}

// Round 4
// 559.154 us; speedup vs baseline: 1.8206x; 1.0486x over previous
//
#include <hip/hip_runtime.h>
#include <hip/hip_bf16.h>
#include <cstddef>
#include <cstdint>

#define TOKENS 4096
#define DMODEL 1024
#define DFFN   2048
#define NEXP   8
#define MAXT_E 72                 // max 128-row expert m-tiles
#define MT_SH  (TOKENS / 128)     // 32 shared m-tiles
#define MT_ALL (MT_SH + MAXT_E)   // 104

typedef __attribute__((ext_vector_type(8))) __bf16 bf16x8;
typedef __attribute__((ext_vector_type(4))) float f4_t;
typedef __attribute__((ext_vector_type(4))) unsigned short us4;

__device__ __forceinline__ unsigned short f2bf(float f) {
  union { float f; unsigned int u; } v; v.f = f;
  unsigned int r = v.u + 0x7FFFu + ((v.u >> 16) & 1u);
  return (unsigned short)(r >> 16);
}

__device__ __forceinline__ void glds16(const void* g, void* l) {
  __builtin_amdgcn_global_load_lds((const __attribute__((address_space(1))) void*)g,
                                   (__attribute__((address_space(3))) void*)l, 16, 0, 0);
}

// ---------------- fused pre-pass: x fp32->bf16 + 6 weight transposes ----------------
// conv: 2048 blocks; transpose tiles 128r x 64c: swg 256, swu 256, swd 256, ewg/ewu/ewd 2048 each
#define CONV_BLKS 2048
__global__ __launch_bounds__(256) void prepass_kernel(
    const float* __restrict__ x, unsigned short* __restrict__ xb,
    const float* __restrict__ swg, unsigned short* __restrict__ swgT,
    const float* __restrict__ swu, unsigned short* __restrict__ swuT,
    const float* __restrict__ swd, unsigned short* __restrict__ swdT,
    const float* __restrict__ ewg, unsigned short* __restrict__ ewgT,
    const float* __restrict__ ewu, unsigned short* __restrict__ ewuT,
    const float* __restrict__ ewd, unsigned short* __restrict__ ewdT) {
  __shared__ float sF[128][65];
  int b = blockIdx.x, tid = threadIdx.x;
  if (b < CONV_BLKS) {
    int i = b * 2048 + tid * 8;
    float4 a = *(const float4*)&x[i];
    float4 c = *(const float4*)&x[i + 4];
    union { unsigned short u[8]; uint4 v; } p;
    p.u[0] = f2bf(a.x); p.u[1] = f2bf(a.y); p.u[2] = f2bf(a.z); p.u[3] = f2bf(a.w);
    p.u[4] = f2bf(c.x); p.u[5] = f2bf(c.y); p.u[6] = f2bf(c.z); p.u[7] = f2bf(c.w);
    *(uint4*)&xb[i] = p.v;
    return;
  }
  b -= CONV_BLKS;
  const float* src; unsigned short* dst; int R, C;
  if (b < 256)       { src = swg; dst = swgT; R = 1024; C = 2048; }
  else if (b < 512)  { b -= 256; src = swu; dst = swuT; R = 1024; C = 2048; }
  else if (b < 768)  { b -= 512; src = swd; dst = swdT; R = 2048; C = 1024; }
  else if (b < 2816) { b -= 768; int e = b >> 8; b &= 255;
                       src = ewg + (size_t)e * (DMODEL * DFFN); dst = ewgT + (size_t)e * (DMODEL * DFFN);
                       R = 1024; C = 2048; }
  else if (b < 4864) { b -= 2816; int e = b >> 8; b &= 255;
                       src = ewu + (size_t)e * (DMODEL * DFFN); dst = ewuT + (size_t)e * (DMODEL * DFFN);
                       R = 1024; C = 2048; }
  else               { b -= 4864; int e = b >> 8; b &= 255;
                       src = ewd + (size_t)e * (DFFN * DMODEL); dst = ewdT + (size_t)e * (DFFN * DMODEL);
                       R = 2048; C = 1024; }
  // tiles: R/128 rows x C/64 cols
  int ntc = C >> 6;
  int tr = b / ntc, tc = b - tr * ntc;
  int r0 = tr * 128, c0 = tc * 64;
#pragma unroll
  for (int it = 0; it < 8; ++it) {
    int r = it * 16 + (tid >> 4);
    int c = (tid & 15) * 4;
    float4 v = *(const float4*)&src[(size_t)(r0 + r) * C + c0 + c];
    sF[r][c + 0] = v.x; sF[r][c + 1] = v.y; sF[r][c + 2] = v.z; sF[r][c + 3] = v.w;
  }
  __syncthreads();
  // write: column cc gets 256B contiguous (4 threads x 64B)
  int cc = tid >> 2, rr = (tid & 3) * 32;
  unsigned short* drow = dst + (size_t)(c0 + cc) * R + r0 + rr;
#pragma unroll
  for (int q = 0; q < 4; ++q) {
    union { unsigned short u[8]; uint4 v; } p;
#pragma unroll
    for (int i = 0; i < 8; ++i) p.u[i] = f2bf(sF[rr + q * 8 + i][cc]);
    *(uint4*)(drow + q * 8) = p.v;
  }
}

// ---------------- router: 1 wave per token ----------------
__global__ __launch_bounds__(256) void router_kernel(
    const float* __restrict__ x, const float* __restrict__ rw,
    int* __restrict__ topi, float* __restrict__ topw,
    int* __restrict__ c_part, float* __restrict__ p_part) {
  __shared__ float sW[DMODEL * NEXP];
  __shared__ int sc[NEXP];
  __shared__ float sp[NEXP];
  for (int i = threadIdx.x; i < DMODEL * NEXP; i += 256) sW[i] = rw[i];
  if (threadIdx.x < NEXP) { sc[threadIdx.x] = 0; sp[threadIdx.x] = 0.f; }
  __syncthreads();
  int wave = threadIdx.x >> 6, lane = threadIdx.x & 63;
  int t = blockIdx.x * 4 + wave;
  const float* xr = x + (size_t)t * DMODEL;
  float acc[NEXP];
#pragma unroll
  for (int e = 0; e < NEXP; ++e) acc[e] = 0.f;
  for (int i = 0; i < DMODEL / 64; ++i) {
    int d = lane + 64 * i;
    float xv = xr[d];
#pragma unroll
    for (int e = 0; e < NEXP; ++e) acc[e] += xv * sW[d * NEXP + e];
  }
#pragma unroll
  for (int off = 32; off > 0; off >>= 1) {
#pragma unroll
    for (int e = 0; e < NEXP; ++e) acc[e] += __shfl_down(acc[e], off, 64);
  }
  if (lane == 0) {
    float m = acc[0];
#pragma unroll
    for (int e = 1; e < NEXP; ++e) m = fmaxf(m, acc[e]);
    float s = 0.f, p[NEXP];
#pragma unroll
    for (int e = 0; e < NEXP; ++e) { p[e] = expf(acc[e] - m); s += p[e]; }
    float inv = 1.f / s;
    int i1 = 0;
#pragma unroll
    for (int e = 1; e < NEXP; ++e) if (acc[e] > acc[i1]) i1 = e;
    int i2 = (i1 == 0) ? 1 : 0;
#pragma unroll
    for (int e = 0; e < NEXP; ++e) if (e != i1 && acc[e] > acc[i2]) i2 = e;
    float w1 = 1.f / (1.f + expf(acc[i2] - acc[i1]));
    topi[2 * t] = i1; topi[2 * t + 1] = i2;
    topw[2 * t] = w1; topw[2 * t + 1] = 1.f - w1;
    atomicAdd(&sc[i1], 1); atomicAdd(&sc[i2], 1);
#pragma unroll
    for (int e = 0; e < NEXP; ++e) atomicAdd(&sp[e], p[e] * inv);
  }
  __syncthreads();
  if (threadIdx.x < NEXP) {
    c_part[blockIdx.x * NEXP + threadIdx.x] = sc[threadIdx.x];
    p_part[blockIdx.x * NEXP + threadIdx.x] = sp[threadIdx.x];
  }
}

// ---------------- scan: offsets + aux + tile list ----------------
__global__ void scan_aux_kernel(const int* __restrict__ c_part,
                                const float* __restrict__ p_part,
                                int* __restrict__ counts, int* __restrict__ offsets,
                                int* __restrict__ te, int* __restrict__ tb,
                                int* __restrict__ ntl,
                                float* __restrict__ aux_out) {
  __shared__ int sc[32][NEXP];
  __shared__ float sp[32][NEXP];
  __shared__ int fc[NEXP];
  __shared__ float fp[NEXP];
  int e = threadIdx.x & 7, g = threadIdx.x >> 3;
  int cs = 0; float ps = 0.f;
  for (int b = g; b < TOKENS / 4; b += 32) { cs += c_part[b * NEXP + e]; ps += p_part[b * NEXP + e]; }
  sc[g][e] = cs; sp[g][e] = ps;
  __syncthreads();
  if (threadIdx.x < NEXP) {
    int c = 0; float p = 0.f;
    for (int gg = 0; gg < 32; ++gg) { c += sc[gg][threadIdx.x]; p += sp[gg][threadIdx.x]; }
    fc[threadIdx.x] = c; fp[threadIdx.x] = p;
    counts[threadIdx.x] = c;
  }
  __syncthreads();
  if (threadIdx.x == 0) {
    int off = 0; float aux = 0.f; int idx = 0;
    for (int ee = 0; ee < NEXP; ++ee) {
      offsets[ee] = off;
      int nt = (fc[ee] + 127) >> 7;
      for (int t = 0; t < nt; ++t) { te[idx] = ee; tb[idx] = t * 128; ++idx; }
      off += fc[ee];
      aux += (float)fc[ee] * fp[ee];
    }
    ntl[0] = idx;
    aux_out[0] = (float)NEXP * aux / ((float)TOKENS * (float)TOKENS);
  }
}

// ---------------- dispatch: compact per-expert lists + per-token slot index ----------------
__global__ void dispatch_kernel(const int* __restrict__ topi, const float* __restrict__ topw,
                                const int* __restrict__ offsets, int* __restrict__ fill,
                                int* __restrict__ token_list, float* __restrict__ weight_list,
                                int* __restrict__ slot_idx) {
  int t = blockIdx.x * 256 + threadIdx.x;
  if (t >= TOKENS) return;
#pragma unroll
  for (int k = 0; k < 2; ++k) {
    int e = topi[2 * t + k]; float w = topw[2 * t + k];
    int pos = atomicAdd(&fill[e], 1);
    int idx = offsets[e] + pos;
    token_list[idx] = t;
    weight_list[idx] = w;
    slot_idx[2 * t + k] = idx;
  }
}

// ---------------- G1: A=W^T(ffn,k), B=x(tok,k); BK=64 as two 32-panels ----------------
__global__ __launch_bounds__(512, 4) void g1_kernel(
    const unsigned short* __restrict__ xb,
    const unsigned short* __restrict__ swgT, const unsigned short* __restrict__ swuT,
    const unsigned short* __restrict__ ewgT, const unsigned short* __restrict__ ewuT,
    const int* __restrict__ counts, const int* __restrict__ offsets,
    const int* __restrict__ te, const int* __restrict__ tb, const int* __restrict__ ntl,
    const int* __restrict__ token_list,
    unsigned short* __restrict__ hbuf) {
  int ff_blk = blockIdx.x & 15;
  int mt = blockIdx.x >> 4;
  int f0 = ff_blk * 128;
  const unsigned short *wgT, *wuT;
  int h_base, tl_base, nvalid;
  bool shared_e;
  if (mt < MT_SH) {
    shared_e = true; wgT = swgT; wuT = swuT;
    h_base = mt * 128; tl_base = 0; nvalid = 128;
  } else {
    int em = mt - MT_SH;
    if (em >= ntl[0]) return;
    int e = te[em], lb = tb[em];
    shared_e = false;
    nvalid = min(128, counts[e] - lb);
    tl_base = offsets[e] + lb;
    h_base = TOKENS + tl_base;
    wgT = ewgT + (size_t)e * (DMODEL * DFFN);
    wuT = ewuT + (size_t)e * (DMODEL * DFFN);
  }
  __shared__ unsigned short sAg[2 * 4096];
  __shared__ unsigned short sAu[2 * 4096];
  __shared__ unsigned short sB[2 * 4096];
  __shared__ int s_tok[128];
  int tid = threadIdx.x;
  if (tid < 128) {
    s_tok[tid] = shared_e ? (h_base + tid) : token_list[tl_base + min(tid, nvalid - 1)];
  }
  __syncthreads();
  int row = tid >> 2;             // 0..127
  int ce = (tid & 3) * 8;
  const unsigned short* pG = wgT + (size_t)(f0 + row) * DMODEL + ce;
  const unsigned short* pU = wuT + (size_t)(f0 + row) * DMODEL + ce;
  const unsigned short* pB = xb + (size_t)s_tok[row] * DMODEL + ce;

  int wv = tid >> 6, lane = tid & 63;
  int wm = wv & 1, wn = wv >> 1;  // wm: ffn half, wn: token quarter
  int lm = lane & 15, quad = lane >> 4;

  f4_t accg[4][2], accu[4][2];
#pragma unroll
  for (int i = 0; i < 4; ++i)
#pragma unroll
    for (int j = 0; j < 2; ++j)
#pragma unroll
      for (int r = 0; r < 4; ++r) { accg[i][j][r] = 0.f; accu[i][j][r] = 0.f; }

  for (int k0 = 0; k0 < DMODEL; k0 += 64) {
#pragma unroll
    for (int p = 0; p < 2; ++p) {
      glds16(pG + k0 + p * 32, &sAg[p * 4096 + tid * 8]);
      glds16(pU + k0 + p * 32, &sAu[p * 4096 + tid * 8]);
      glds16(pB + k0 + p * 32, &sB[p * 4096 + tid * 8]);
    }
    __syncthreads();
#pragma unroll
    for (int p = 0; p < 2; ++p) {
      bf16x8 b0 = *(const bf16x8*)&sB[p * 4096 + (wn * 32 + lm) * 32 + quad * 8];
      bf16x8 b1 = *(const bf16x8*)&sB[p * 4096 + (wn * 32 + 16 + lm) * 32 + quad * 8];
#pragma unroll
      for (int i = 0; i < 4; ++i) {
        bf16x8 ag = *(const bf16x8*)&sAg[p * 4096 + (wm * 64 + i * 16 + lm) * 32 + quad * 8];
        bf16x8 au = *(const bf16x8*)&sAu[p * 4096 + (wm * 64 + i * 16 + lm) * 32 + quad * 8];
        accg[i][0] = __builtin_amdgcn_mfma_f32_16x16x32_bf16(ag, b0, accg[i][0], 0, 0, 0);
        accg[i][1] = __builtin_amdgcn_mfma_f32_16x16x32_bf16(ag, b1, accg[i][1], 0, 0, 0);
        accu[i][0] = __builtin_amdgcn_mfma_f32_16x16x32_bf16(au, b0, accu[i][0], 0, 0, 0);
        accu[i][1] = __builtin_amdgcn_mfma_f32_16x16x32_bf16(au, b1, accu[i][1], 0, 0, 0);
      }
    }
    __syncthreads();
  }
#pragma unroll
  for (int j = 0; j < 2; ++j) {
    int tok = wn * 32 + j * 16 + lm;
    if (tok < nvalid) {
      unsigned short* hrow = hbuf + (size_t)(h_base + tok) * DFFN + f0 + wm * 64 + quad * 4;
#pragma unroll
      for (int i = 0; i < 4; ++i) {
        us4 h4;
#pragma unroll
        for (int r = 0; r < 4; ++r) {
          float g = accg[i][j][r], u = accu[i][j][r];
          h4[r] = f2bf(g / (1.f + __expf(-g)) * u);
        }
        *(us4*)(hrow + i * 16) = h4;
      }
    }
  }
}

// ---------------- G2: down-proj; shared->out direct, expert->eres (no atomics) ----------------
__global__ __launch_bounds__(512, 4) void g2_kernel(
    const unsigned short* __restrict__ hbuf,
    const unsigned short* __restrict__ swdT, const unsigned short* __restrict__ ewdT,
    const int* __restrict__ counts, const int* __restrict__ offsets,
    const int* __restrict__ te, const int* __restrict__ tb, const int* __restrict__ ntl,
    const float* __restrict__ weight_list,
    float* __restrict__ out, float* __restrict__ eres) {
  int nt_blk = blockIdx.x & 7;
  int mt = blockIdx.x >> 3;
  int d0 = nt_blk * 128;
  const unsigned short* wdT;
  int h_base, tl_base, nvalid;
  bool shared_e;
  if (mt < MT_SH) {
    shared_e = true; wdT = swdT;
    h_base = mt * 128; tl_base = 0; nvalid = 128;
  } else {
    int em = mt - MT_SH;
    if (em >= ntl[0]) return;
    int e = te[em], lb = tb[em];
    shared_e = false;
    nvalid = min(128, counts[e] - lb);
    tl_base = offsets[e] + lb;
    h_base = TOKENS + tl_base;
    wdT = ewdT + (size_t)e * (DFFN * DMODEL);
  }
  __shared__ unsigned short sA[2 * 4096];
  __shared__ unsigned short sB[2 * 4096];
  __shared__ float s_w[128];
  int tid = threadIdx.x;
  if (tid < 128) {
    s_w[tid] = shared_e ? 1.f : weight_list[tl_base + min(tid, nvalid - 1)];
  }
  __syncthreads();
  int row = tid >> 2;
  int ce = (tid & 3) * 8;
  const unsigned short* pA = hbuf + (size_t)(h_base + row) * DFFN + ce;
  const unsigned short* pB = wdT + (size_t)(d0 + row) * DFFN + ce;

  int wv = tid >> 6, lane = tid & 63;
  int wm = wv & 1, wn = wv >> 1;
  int lm = lane & 15, quad = lane >> 4;

  f4_t acc[4][2];
#pragma unroll
  for (int i = 0; i < 4; ++i)
#pragma unroll
    for (int j = 0; j < 2; ++j)
#pragma unroll
      for (int r = 0; r < 4; ++r) acc[i][j][r] = 0.f;

  for (int k0 = 0; k0 < DFFN; k0 += 64) {
#pragma unroll
    for (int p = 0; p < 2; ++p) {
      glds16(pA + k0 + p * 32, &sA[p * 4096 + tid * 8]);
      glds16(pB + k0 + p * 32, &sB[p * 4096 + tid * 8]);
    }
    __syncthreads();
#pragma unroll
    for (int p = 0; p < 2; ++p) {
      bf16x8 b0 = *(const bf16x8*)&sB[p * 4096 + (wn * 32 + lm) * 32 + quad * 8];
      bf16x8 b1 = *(const bf16x8*)&sB[p * 4096 + (wn * 32 + 16 + lm) * 32 + quad * 8];
#pragma unroll
      for (int i = 0; i < 4; ++i) {
        bf16x8 a = *(const bf16x8*)&sA[p * 4096 + (wm * 64 + i * 16 + lm) * 32 + quad * 8];
        acc[i][0] = __builtin_amdgcn_mfma_f32_16x16x32_bf16(a, b0, acc[i][0], 0, 0, 0);
        acc[i][1] = __builtin_amdgcn_mfma_f32_16x16x32_bf16(a, b1, acc[i][1], 0, 0, 0);
      }
    }
    __syncthreads();
  }
  // C/D: col(dmodel) = lane&15 (within wn*32 + j*16), row(token) = wm*64 + i*16 + quad*4 + r
#pragma unroll
  for (int i = 0; i < 4; ++i)
#pragma unroll
    for (int r = 0; r < 4; ++r) {
      int rw = wm * 64 + i * 16 + quad * 4 + r;
      if (rw < nvalid) {
        float w = s_w[rw];
        if (shared_e) {
          float* orow = out + (size_t)(h_base + rw) * DMODEL + d0 + wn * 32 + lm;
          orow[0] = acc[i][0][r];
          orow[16] = acc[i][1][r];
        } else {
          float* erow = eres + (size_t)(tl_base + rw) * DMODEL + d0 + wn * 32 + lm;
          erow[0] = w * acc[i][0][r];
          erow[16] = w * acc[i][1][r];
        }
      }
    }
}

// ---------------- combine: out[t] += eres[s1] + eres[s2] ----------------
__global__ __launch_bounds__(256) void combine_kernel(float* __restrict__ out,
                                                      const float* __restrict__ eres,
                                                      const int* __restrict__ slot_idx) {
  int t = blockIdx.x;
  int s1 = slot_idx[2 * t], s2 = slot_idx[2 * t + 1];
  int d = threadIdx.x * 4;
  float4 o = *(float4*)&out[(size_t)t * DMODEL + d];
  float4 a = *(const float4*)&eres[(size_t)s1 * DMODEL + d];
  float4 b = *(const float4*)&eres[(size_t)s2 * DMODEL + d];
  o.x += a.x + b.x; o.y += a.y + b.y; o.z += a.z + b.z; o.w += a.w + b.w;
  *(float4*)&out[(size_t)t * DMODEL + d] = o;
}

extern "C" void kernel_launch(void* const* d_in, const int* in_sizes, int n_in,
                              void* d_out, int out_size, void* d_ws, size_t ws_size,
                              hipStream_t stream) {
  const float* x   = (const float*)d_in[0];
  const float* swg = (const float*)d_in[1];
  const float* swu = (const float*)d_in[2];
  const float* swd = (const float*)d_in[3];
  const float* ewg = (const float*)d_in[4];
  const float* ewu = (const float*)d_in[5];
  const float* ewd = (const float*)d_in[6];
  const float* rw  = (const float*)d_in[7];
  float* out = (float*)d_out;

  char* ws = (char*)d_ws;
  const size_t MB = 1048576;
  int*   fill     = (int*)(ws + 0);
  int*   counts   = (int*)(ws + 64);
  int*   offsets  = (int*)(ws + 128);
  int*   ntl      = (int*)(ws + 192);
  int*   te       = (int*)(ws + 256);
  int*   tb       = (int*)(ws + 1024);
  int*   topi     = (int*)(ws + 65536);
  float* topw     = (float*)(ws + 98304);
  int*   c_part   = (int*)(ws + 131072);
  float* p_part   = (float*)(ws + 163840);
  int*   tok_list = (int*)(ws + 196608);
  float* w_list   = (float*)(ws + 229376);
  int*   slot_idx = (int*)(ws + 262144);                     // 32 KB
  unsigned short* xb   = (unsigned short*)(ws + 1 * MB);     // 8.4 MB
  unsigned short* swgT = (unsigned short*)(ws + 16 * MB);
  unsigned short* swuT = (unsigned short*)(ws + 20 * MB);
  unsigned short* swdT = (unsigned short*)(ws + 24 * MB);
  unsigned short* ewgT = (unsigned short*)(ws + 28 * MB);    // 32 MB (g1-only)
  unsigned short* ewuT = (unsigned short*)(ws + 60 * MB);    // 32 MB (g1-only)
  unsigned short* ewdT = (unsigned short*)(ws + 92 * MB);
  float*          eres = (float*)(ws + 28 * MB);             // 34 MB, overlaps ewgT/ewuT (g2-time only)
  unsigned short* hbuf = (unsigned short*)(ws + 124 * MB);

  hipMemsetAsync(ws, 0, 32, stream);  // fill[]

  prepass_kernel<<<CONV_BLKS + 6912, 256, 0, stream>>>(
      x, xb, swg, swgT, swu, swuT, swd, swdT, ewg, ewgT, ewu, ewuT, ewd, ewdT);
  router_kernel<<<TOKENS / 4, 256, 0, stream>>>(x, rw, topi, topw, c_part, p_part);
  scan_aux_kernel<<<1, 256, 0, stream>>>(c_part, p_part, counts, offsets, te, tb, ntl,
                                         out + (size_t)TOKENS * DMODEL);
  dispatch_kernel<<<TOKENS / 256, 256, 0, stream>>>(topi, topw, offsets, fill,
                                                    tok_list, w_list, slot_idx);

  g1_kernel<<<MT_ALL * 16, 512, 0, stream>>>(xb, swgT, swuT, ewgT, ewuT,
                                             counts, offsets, te, tb, ntl, tok_list, hbuf);
  g2_kernel<<<MT_ALL * 8, 512, 0, stream>>>(hbuf, swdT, ewdT,
                                            counts, offsets, te, tb, ntl, w_list, out, eres);
  combine_kernel<<<TOKENS, 256, 0, stream>>>(out, eres, slot_idx);
}